// Round 1
// baseline (13418.221 us; speedup 1.0000x reference)
//
#include <hip/hip_runtime.h>
#include <hip/hip_bf16.h>

// Problem constants (MoELayer: B=4, T=2048, D=1024, E=8, H=2048, K=2)
#define NB    4
#define NTT   2048
#define ND    1024
#define NE    8
#define NH    2048
#define NKK   2
#define NTOK  (NB*NTT)       // 8192 tokens
#define NPAIR (NTOK*NKK)     // 16384 (token, expert) pairs

// ---------------- kernel 1: router logits -> top2 -> softmax -> counts ----------------
__global__ __launch_bounds__(256) void router_topk(
    const float* __restrict__ x, const float* __restrict__ rw,
    int* __restrict__ topk_idx, float* __restrict__ topk_w, int* __restrict__ counts)
{
    const int n   = blockIdx.x;
    const int tid = threadIdx.x;
    const int e   = tid >> 5;       // 8 experts x 32 threads
    const int l   = tid & 31;
    const float* xr = x  + (size_t)n * ND;
    const float* wr = rw + (size_t)e * ND;
    float acc = 0.f;
    #pragma unroll 4
    for (int d = l; d < ND; d += 32) acc += xr[d] * wr[d];

    __shared__ float part[NE][33];
    __shared__ float logits[NE];
    part[e][l] = acc;
    __syncthreads();
    if (tid < NE) {
        float s = 0.f;
        #pragma unroll
        for (int i = 0; i < 32; ++i) s += part[tid][i];
        logits[tid] = s;
    }
    __syncthreads();
    if (tid == 0) {
        int i0 = 0; float v0 = logits[0];
        #pragma unroll
        for (int i = 1; i < NE; ++i) { float v = logits[i]; if (v > v0) { v0 = v; i0 = i; } }
        int i1 = -1; float v1 = -3.4e38f;
        #pragma unroll
        for (int i = 0; i < NE; ++i) {
            if (i == i0) continue;
            float v = logits[i]; if (v > v1) { v1 = v; i1 = i; }
        }
        float w0 = 1.f / (1.f + expf(v1 - v0));   // softmax over [v0, v1], v0 >= v1
        topk_idx[n*2]   = i0;  topk_idx[n*2+1] = i1;
        topk_w [n*2]    = w0;  topk_w [n*2+1]  = 1.f - w0;
        atomicAdd(&counts[i0], 1);
        atomicAdd(&counts[i1], 1);
    }
}

// ---------------- kernel 2: prefix sum over E=8 counts ----------------
__global__ void prefix_offsets(int* __restrict__ ctrl)
{
    // ctrl[0..7]=counts, ctrl[8..15]=cursors, ctrl[16..24]=offsets
    int* counts  = ctrl;
    int* cursors = ctrl + 8;
    int* offsets = ctrl + 16;
    int s = 0;
    for (int e = 0; e < NE; ++e) { offsets[e] = s; s += counts[e]; cursors[e] = 0; }
    offsets[NE] = s;
}

// ---------------- kernel 3: scatter tokens into per-expert buckets ----------------
__global__ __launch_bounds__(256) void scatter_tokens(
    const int* __restrict__ topk_idx, const float* __restrict__ topk_w,
    int* __restrict__ ctrl, int* __restrict__ bucket_tok, float* __restrict__ bucket_gw)
{
    const int n = blockIdx.x * blockDim.x + threadIdx.x;
    if (n >= NTOK) return;
    int* cursors = ctrl + 8;
    const int* offsets = ctrl + 16;
    #pragma unroll
    for (int k = 0; k < NKK; ++k) {
        int e = topk_idx[n*2 + k];
        int pos = offsets[e] + atomicAdd(&cursors[e], 1);
        bucket_tok[pos] = n;
        bucket_gw [pos] = topk_w[n*2 + k];
    }
}

// ---------------- kernel 4: fused expert MLP (fp32 baseline) ----------------
// Block: 64 tokens of one expert, 512 threads (8 waves). Wave w owns tokens 8w..8w+7.
// Thread owns y acc for its 8 tokens x 16 d-columns (d = lane + 64*j).
// Loop H in 64-chunks: phase1 h = x @ w1chunk (w1 staged in LDS, lane = hh),
// relu^2 -> hbuf(LDS, wave-local), phase2 y += hbuf @ w2chunk (w2 staged in LDS).
#define TT 64
#define HC 64

__global__ __launch_bounds__(512, 2) void moe_mlp(
    const float* __restrict__ x, const float* __restrict__ w1, const float* __restrict__ w2,
    const int* __restrict__ bucket_tok, const float* __restrict__ bucket_gw,
    const int* __restrict__ ctrl, float* __restrict__ out)
{
    const int e = blockIdx.y;
    const int* offsets = ctrl + 16;
    const int beg = offsets[e];
    const int cnt = offsets[e+1] - beg;
    const int tile = blockIdx.x;
    if (tile * TT >= cnt) return;

    extern __shared__ float smem[];
    float* wstage = smem;            // 8192 floats (32KB): w1 sub [128d][64h] or w2 sub [8h][1024d]
    float* hbuf   = smem + 8192;     // 4096 floats (16KB): [64 tok][64 hh]

    const int tid  = threadIdx.x;
    const int wave = tid >> 6;
    const int lane = tid & 63;

    int tok[8]; float gw[8]; bool valid[8];
    const float* xrow[8];
    #pragma unroll
    for (int t = 0; t < 8; ++t) {
        int s = tile*TT + wave*8 + t;
        valid[t] = (s < cnt);
        int bi = beg + (valid[t] ? s : 0);
        tok[t]  = bucket_tok[bi];
        gw[t]   = bucket_gw[bi];
        xrow[t] = x + (size_t)tok[t] * ND;
    }

    const float* w1e = w1 + (size_t)e * ND * NH;   // [D=1024][H=2048]
    const float* w2e = w2 + (size_t)e * NH * ND;   // [H=2048][D=1024]

    float acc[8][16];
    #pragma unroll
    for (int t = 0; t < 8; ++t)
        #pragma unroll
        for (int j = 0; j < 16; ++j) acc[t][j] = 0.f;

    for (int hb = 0; hb < NH; hb += HC) {
        // ---------- phase 1: hacc[t] = dot(x[t], w1[:, hb+lane]) ----------
        float hacc[8] = {0,0,0,0,0,0,0,0};
        for (int s4 = 0; s4 < 8; ++s4) {            // d-subchunks of 128
            __syncthreads();                         // wstage reuse safe
            const int dbase = s4 * 128;
            #pragma unroll
            for (int r = 0; r < 4; ++r) {            // stage w1 sub: [128][64] floats
                int i4 = r*512 + tid;                // 0..2047 float4s
                int dd = i4 >> 4, h4 = i4 & 15;
                *(float4*)(wstage + (size_t)i4*4) =
                    *(const float4*)(w1e + (size_t)(dbase+dd)*NH + hb + h4*4);
            }
            __syncthreads();
            for (int d4 = 0; d4 < 32; ++d4) {
                float4 xv[8];
                #pragma unroll
                for (int t = 0; t < 8; ++t)
                    xv[t] = *(const float4*)(xrow[t] + dbase + d4*4);
                #pragma unroll
                for (int q = 0; q < 4; ++q) {
                    float wv = wstage[(d4*4+q)*64 + lane];   // lane-consecutive: conflict-free
                    #pragma unroll
                    for (int t = 0; t < 8; ++t) {
                        float xq = (q==0)?xv[t].x:(q==1)?xv[t].y:(q==2)?xv[t].z:xv[t].w;
                        hacc[t] = fmaf(xq, wv, hacc[t]);
                    }
                }
            }
        }
        // relu^2 -> hbuf (wave-local rows; next reads are same-wave, waitcnt-ordered)
        #pragma unroll
        for (int t = 0; t < 8; ++t) {
            float hv = fmaxf(hacc[t], 0.f);
            hbuf[(wave*8+t)*64 + lane] = hv * hv;
        }
        // ---------- phase 2: acc[t][j] += a[t][hh] * w2[hh][lane+64j] ----------
        for (int s2 = 0; s2 < 8; ++s2) {            // hh-subchunks of 8
            __syncthreads();
            #pragma unroll
            for (int r = 0; r < 4; ++r) {            // stage w2 sub: [8][1024] floats
                int i4 = r*512 + tid;
                int hh = i4 >> 8, d4i = i4 & 255;
                *(float4*)(wstage + (size_t)i4*4) =
                    *(const float4*)(w2e + (size_t)(hb + s2*8 + hh)*ND + d4i*4);
            }
            __syncthreads();
            for (int hh = 0; hh < 8; ++hh) {
                float av[8];
                #pragma unroll
                for (int t = 0; t < 8; ++t) av[t] = hbuf[(wave*8+t)*64 + s2*8 + hh];
                #pragma unroll
                for (int j = 0; j < 16; ++j) {
                    float wv = wstage[hh*1024 + lane + 64*j];  // lane-consecutive: conflict-free
                    #pragma unroll
                    for (int t = 0; t < 8; ++t) acc[t][j] = fmaf(av[t], wv, acc[t][j]);
                }
            }
        }
    }
    // ---------- epilogue: gate-weighted atomic accumulate ----------
    #pragma unroll
    for (int t = 0; t < 8; ++t) {
        if (!valid[t]) continue;
        float g = gw[t];
        float* orow = out + (size_t)tok[t] * ND + lane;
        #pragma unroll
        for (int j = 0; j < 16; ++j) atomicAdd(orow + 64*j, g * acc[t][j]);
    }
}

// ---------------- launch ----------------
extern "C" void kernel_launch(void* const* d_in, const int* in_sizes, int n_in,
                              void* d_out, int out_size, void* d_ws, size_t ws_size,
                              hipStream_t stream) {
    const float* x  = (const float*)d_in[0];
    const float* rw = (const float*)d_in[1];
    const float* w1 = (const float*)d_in[2];
    const float* w2 = (const float*)d_in[3];
    float* out = (float*)d_out;

    // workspace layout (~257KB)
    int*   ctrl       = (int*)d_ws;                    // [0..7] counts, [8..15] cursors, [16..24] offsets
    int*   topk_idx   = ctrl + 32;                     // NPAIR ints
    float* topk_w     = (float*)(topk_idx + NPAIR);    // NPAIR floats
    int*   bucket_tok = (int*)(topk_w + NPAIR);        // NPAIR ints
    float* bucket_gw  = (float*)(bucket_tok + NPAIR);  // NPAIR floats

    hipMemsetAsync(d_out, 0, (size_t)NTOK * ND * sizeof(float), stream);
    hipMemsetAsync(d_ws, 0, 128, stream);              // zero counts/cursors/offsets

    router_topk<<<NTOK, 256, 0, stream>>>(x, rw, topk_idx, topk_w, ctrl);
    prefix_offsets<<<1, 1, 0, stream>>>(ctrl);
    scatter_tokens<<<NTOK/256, 256, 0, stream>>>(topk_idx, topk_w, ctrl, bucket_tok, bucket_gw);

    size_t shbytes = (8192 + 4096) * sizeof(float);    // 48KB dynamic LDS
    dim3 grid(NPAIR/TT, NE);                           // worst-case tiles per expert x experts
    moe_mlp<<<grid, 512, shbytes, stream>>>(x, w1, w2, bucket_tok, bucket_gw, ctrl, out);
}

// Round 3
// 1035.863 us; speedup vs baseline: 12.9537x; 12.9537x over previous
//
#include <hip/hip_runtime.h>
#include <hip/hip_bf16.h>

// MoELayer: B=4, T=2048, D=1024, E=8, H=2048, K=2
#define ND    1024
#define NE    8
#define NH    2048
#define NKK   2
#define NTOK  8192
#define NPAIR (NTOK*NKK)
#define TT    64          // tokens per block (mfma path)
#define HC    128         // h-chunk
#define XB_S  1032        // x LDS row stride (bf16): 2064 B, 16B-aligned
#define AL_S  136         // a LDS row stride (bf16): 272 B, 16B-aligned

typedef unsigned short u16;
typedef __attribute__((ext_vector_type(8))) short bf16x8;
typedef __attribute__((ext_vector_type(4))) float f32x4;

__device__ __forceinline__ u16 f2bf(float f) {
    union { float f; unsigned u; } v; v.f = f;
    return (u16)((v.u + 0x7fffu + ((v.u >> 16) & 1u)) >> 16);   // RNE
}

// ---------------- kernel 1: router logits -> top2 -> softmax -> counts ----------------
__global__ __launch_bounds__(256) void router_topk(
    const float* __restrict__ x, const float* __restrict__ rw,
    int* __restrict__ topk_idx, float* __restrict__ topk_w, int* __restrict__ counts)
{
    const int n   = blockIdx.x;
    const int tid = threadIdx.x;
    const int e   = tid >> 5;
    const int l   = tid & 31;
    const float* xr = x  + (size_t)n * ND;
    const float* wr = rw + (size_t)e * ND;
    float acc = 0.f;
    #pragma unroll 4
    for (int d = l; d < ND; d += 32) acc += xr[d] * wr[d];

    __shared__ float part[NE][33];
    __shared__ float logits[NE];
    part[e][l] = acc;
    __syncthreads();
    if (tid < NE) {
        float s = 0.f;
        #pragma unroll
        for (int i = 0; i < 32; ++i) s += part[tid][i];
        logits[tid] = s;
    }
    __syncthreads();
    if (tid == 0) {
        int i0 = 0; float v0 = logits[0];
        #pragma unroll
        for (int i = 1; i < NE; ++i) { float v = logits[i]; if (v > v0) { v0 = v; i0 = i; } }
        int i1 = -1; float v1 = -3.4e38f;
        #pragma unroll
        for (int i = 0; i < NE; ++i) {
            if (i == i0) continue;
            float v = logits[i]; if (v > v1) { v1 = v; i1 = i; }
        }
        float w0 = 1.f / (1.f + expf(v1 - v0));
        topk_idx[n*2]   = i0;  topk_idx[n*2+1] = i1;
        topk_w [n*2]    = w0;  topk_w [n*2+1]  = 1.f - w0;
        atomicAdd(&counts[i0], 1);
        atomicAdd(&counts[i1], 1);
    }
}

// ---------------- kernel 2: prefix sum over E=8 counts ----------------
__global__ void prefix_offsets(int* __restrict__ ctrl)
{
    int* counts  = ctrl;
    int* cursors = ctrl + 8;
    int* offsets = ctrl + 16;
    int s = 0;
    for (int e = 0; e < NE; ++e) { offsets[e] = s; s += counts[e]; cursors[e] = 0; }
    offsets[NE] = s;
}

// ---------------- kernel 3: scatter tokens into per-expert buckets ----------------
__global__ __launch_bounds__(256) void scatter_tokens(
    const int* __restrict__ topk_idx, const float* __restrict__ topk_w,
    int* __restrict__ ctrl, int* __restrict__ bucket_tok, float* __restrict__ bucket_gw)
{
    const int n = blockIdx.x * blockDim.x + threadIdx.x;
    if (n >= NTOK) return;
    int* cursors = ctrl + 8;
    const int* offsets = ctrl + 16;
    #pragma unroll
    for (int k = 0; k < NKK; ++k) {
        int e = topk_idx[n*2 + k];
        int pos = offsets[e] + atomicAdd(&cursors[e], 1);
        bucket_tok[pos] = n;
        bucket_gw [pos] = topk_w[n*2 + k];
    }
}

// ---------------- kernel T: transpose + fp32->bf16 convert ----------------
// src: [E][R][C] f32  ->  dst: [E][C][R] bf16. 64x64 tiles via LDS.
__global__ __launch_bounds__(256) void transpose_cvt(
    const float* __restrict__ src, u16* __restrict__ dst, int R, int C)
{
    __shared__ float tb[64][65];
    const int tpc = C >> 6;
    const int tr = blockIdx.x / tpc;
    const int tc = blockIdx.x % tpc;
    src += (size_t)blockIdx.y * R * C;
    dst += (size_t)blockIdx.y * R * C;
    const int tid = threadIdx.x;
    #pragma unroll
    for (int i = 0; i < 4; ++i) {
        int idx = i*256 + tid;
        int r = idx >> 4, c4 = (idx & 15) * 4;
        float4 v = *(const float4*)(src + (size_t)(tr*64 + r)*C + tc*64 + c4);
        tb[r][c4] = v.x; tb[r][c4+1] = v.y; tb[r][c4+2] = v.z; tb[r][c4+3] = v.w;
    }
    __syncthreads();
    #pragma unroll
    for (int i = 0; i < 2; ++i) {
        int idx = i*256 + tid;
        int c = idx >> 3, s8 = (idx & 7) * 8;
        union { u16 u[8]; uint4 v; } pk;
        #pragma unroll
        for (int j = 0; j < 8; ++j) pk.u[j] = f2bf(tb[s8 + j][c]);
        *(uint4*)(dst + (size_t)(tc*64 + c)*R + tr*64 + s8) = pk.v;
    }
}

// ---------------- kernel 4: fused MoE MLP, bf16 MFMA (conservative rewrite) ----------------
// Block: 64 tokens of one expert, 512 threads (8 waves).
// Phase A (per 128-h chunk): wave wv owns htile wv (16 h rows) x all 4 ttiles:
//   C1 = W1^T_slice (A, global) x X^T (B, LDS).  D row=4*(lane>>4)+r (h), col=lane&15 (token).
//   relu^2 -> albuf[token][h_local] bf16.
// Phase B: wave wv owns d strip [wv*128, +128): Y^T accum, A=W2^T (global), B=albuf.
// Epilogue: direct gate-weighted atomicAdd from accY (no LDS transpose).
__global__ __launch_bounds__(512) void moe_mlp_mfma(
    const float* __restrict__ x, const u16* __restrict__ w1t, const u16* __restrict__ w2t,
    const int* __restrict__ bucket_tok, const float* __restrict__ bucket_gw,
    const int* __restrict__ ctrl, float* __restrict__ out)
{
    const int e = blockIdx.x;
    const int* offsets = ctrl + 16;
    const int beg = offsets[e];
    const int cnt = offsets[e+1] - beg;
    const int tile = blockIdx.y;
    if (tile * TT >= cnt) return;

    extern __shared__ u16 smem_u[];
    u16* xb    = smem_u;               // [64][XB_S]
    u16* albuf = smem_u + 64 * XB_S;   // [64][AL_S]

    const int tid  = threadIdx.x;
    const int wv   = tid >> 6;
    const int lane = tid & 63;
    const int l15  = lane & 15;
    const int grp  = lane >> 4;        // 0..3
    const int kl   = grp * 8;          // k-offset within fragment

    // ---- stage x tile (fp32 -> bf16, once) ----
    {
        const int t = tid >> 3, part = tid & 7;
        int s = tile * TT + t;
        int bi = beg + (s < cnt ? s : cnt - 1);
        int p = bucket_tok[bi];
        const float* xr = x + (size_t)p * ND;
        #pragma unroll 4
        for (int i = 0; i < 32; ++i) {
            int d = part * 4 + i * 32;
            float4 xv = *(const float4*)(xr + d);
            ushort4 u4;
            u4.x = f2bf(xv.x); u4.y = f2bf(xv.y); u4.z = f2bf(xv.z); u4.w = f2bf(xv.w);
            *(ushort4*)&xb[t * XB_S + d] = u4;
        }
    }
    __syncthreads();

    const u16* w1t_e = w1t + (size_t)e * NH * ND;   // [H][D] bf16
    const u16* w2t_e = w2t + (size_t)e * ND * NH;   // [D][H] bf16
    const int dbase = wv * 128;                     // phase-B d strip

    f32x4 accY[8][4];
    #pragma unroll
    for (int dt = 0; dt < 8; ++dt)
        #pragma unroll
        for (int tt = 0; tt < 4; ++tt) accY[dt][tt] = 0;

    for (int hc = 0; hc < NH; hc += HC) {
        // ---- phase A: h rows [hc + wv*16, +16) x all 64 tokens ----
        f32x4 c1[4];
        #pragma unroll
        for (int tt = 0; tt < 4; ++tt) c1[tt] = 0;
        const u16* ap = w1t_e + (size_t)(hc + wv*16 + l15) * ND + kl;
        for (int ks = 0; ks < 32; ++ks) {
            bf16x8 a = *(const bf16x8*)(ap + ks*32);
            #pragma unroll
            for (int tt = 0; tt < 4; ++tt) {
                bf16x8 b = *(const bf16x8*)&xb[(tt*16 + l15) * XB_S + ks*32 + kl];
                c1[tt] = __builtin_amdgcn_mfma_f32_16x16x32_bf16(a, b, c1[tt], 0,0,0);
            }
        }
        // relu^2 -> albuf[token][h_local];  D: row(h)=4*grp+r, col(token)=l15
        #pragma unroll
        for (int tt = 0; tt < 4; ++tt)
            #pragma unroll
            for (int r = 0; r < 4; ++r) {
                float v = fmaxf(c1[tt][r], 0.f);
                albuf[(tt*16 + l15) * AL_S + (wv*16 + grp*4 + r)] = f2bf(v * v);
            }
        __syncthreads();

        // ---- phase B: accumulate Y^T over this chunk's K=128 ----
        #pragma unroll
        for (int ks = 0; ks < 4; ++ks) {
            bf16x8 bb[4];
            #pragma unroll
            for (int tt = 0; tt < 4; ++tt)
                bb[tt] = *(const bf16x8*)&albuf[(tt*16 + l15) * AL_S + ks*32 + kl];
            const u16* w2p = w2t_e + (size_t)(dbase + l15) * NH + hc + ks*32 + kl;
            #pragma unroll
            for (int dt = 0; dt < 8; ++dt) {
                bf16x8 a = *(const bf16x8*)(w2p + (size_t)dt * 16 * NH);
                #pragma unroll
                for (int tt = 0; tt < 4; ++tt)
                    accY[dt][tt] = __builtin_amdgcn_mfma_f32_16x16x32_bf16(a, bb[tt], accY[dt][tt], 0,0,0);
            }
        }
        __syncthreads();   // albuf consumed; safe to overwrite next chunk
    }

    // ---- epilogue: direct gate-weighted atomicAdd from registers ----
    // accY[dt][tt]: Y^T tile; lane holds rows d_local = grp*4 + r, col token = l15.
    #pragma unroll
    for (int tt = 0; tt < 4; ++tt) {
        int s = tile * TT + tt*16 + l15;
        if (s >= cnt) continue;
        int p = bucket_tok[beg + s];
        float g = bucket_gw[beg + s];
        float* orow = out + (size_t)p * ND + dbase + grp*4;
        #pragma unroll
        for (int dt = 0; dt < 8; ++dt)
            #pragma unroll
            for (int r = 0; r < 4; ++r)
                atomicAdd(orow + dt*16 + r, g * accY[dt][tt][r]);
    }
}

// ---------------- fallback: round-1 fp32 MLP (used if ws too small) ----------------
__global__ __launch_bounds__(512, 2) void moe_mlp(
    const float* __restrict__ x, const float* __restrict__ w1, const float* __restrict__ w2,
    const int* __restrict__ bucket_tok, const float* __restrict__ bucket_gw,
    const int* __restrict__ ctrl, float* __restrict__ out)
{
    const int e = blockIdx.y;
    const int* offsets = ctrl + 16;
    const int beg = offsets[e];
    const int cnt = offsets[e+1] - beg;
    const int tile = blockIdx.x;
    if (tile * 64 >= cnt) return;

    extern __shared__ float smem[];
    float* wstage = smem;
    float* hbuf   = smem + 8192;

    const int tid  = threadIdx.x;
    const int wave = tid >> 6;
    const int lane = tid & 63;

    int tok[8]; float gw[8]; bool valid[8];
    const float* xrow[8];
    #pragma unroll
    for (int t = 0; t < 8; ++t) {
        int s = tile*64 + wave*8 + t;
        valid[t] = (s < cnt);
        int bi = beg + (valid[t] ? s : 0);
        tok[t]  = bucket_tok[bi];
        gw[t]   = bucket_gw[bi];
        xrow[t] = x + (size_t)tok[t] * ND;
    }
    const float* w1e = w1 + (size_t)e * ND * NH;
    const float* w2e = w2 + (size_t)e * NH * ND;

    float acc[8][16];
    #pragma unroll
    for (int t = 0; t < 8; ++t)
        #pragma unroll
        for (int j = 0; j < 16; ++j) acc[t][j] = 0.f;

    for (int hb = 0; hb < NH; hb += 64) {
        float hacc[8] = {0,0,0,0,0,0,0,0};
        for (int s4 = 0; s4 < 8; ++s4) {
            __syncthreads();
            const int dbase = s4 * 128;
            #pragma unroll
            for (int r = 0; r < 4; ++r) {
                int i4 = r*512 + tid;
                int dd = i4 >> 4, h4 = i4 & 15;
                *(float4*)(wstage + (size_t)i4*4) =
                    *(const float4*)(w1e + (size_t)(dbase+dd)*NH + hb + h4*4);
            }
            __syncthreads();
            for (int d4 = 0; d4 < 32; ++d4) {
                float4 xv[8];
                #pragma unroll
                for (int t = 0; t < 8; ++t)
                    xv[t] = *(const float4*)(xrow[t] + dbase + d4*4);
                #pragma unroll
                for (int q = 0; q < 4; ++q) {
                    float wvv = wstage[(d4*4+q)*64 + lane];
                    #pragma unroll
                    for (int t = 0; t < 8; ++t) {
                        float xq = (q==0)?xv[t].x:(q==1)?xv[t].y:(q==2)?xv[t].z:xv[t].w;
                        hacc[t] = fmaf(xq, wvv, hacc[t]);
                    }
                }
            }
        }
        #pragma unroll
        for (int t = 0; t < 8; ++t) {
            float hv = fmaxf(hacc[t], 0.f);
            hbuf[(wave*8+t)*64 + lane] = hv * hv;
        }
        for (int s2 = 0; s2 < 8; ++s2) {
            __syncthreads();
            #pragma unroll
            for (int r = 0; r < 4; ++r) {
                int i4 = r*512 + tid;
                int hh = i4 >> 8, d4i = i4 & 255;
                *(float4*)(wstage + (size_t)i4*4) =
                    *(const float4*)(w2e + (size_t)(hb + s2*8 + hh)*ND + d4i*4);
            }
            __syncthreads();
            for (int hh = 0; hh < 8; ++hh) {
                float av[8];
                #pragma unroll
                for (int t = 0; t < 8; ++t) av[t] = hbuf[(wave*8+t)*64 + s2*8 + hh];
                #pragma unroll
                for (int j = 0; j < 16; ++j) {
                    float wvv = wstage[hh*1024 + lane + 64*j];
                    #pragma unroll
                    for (int t = 0; t < 8; ++t) acc[t][j] = fmaf(av[t], wvv, acc[t][j]);
                }
            }
        }
    }
    #pragma unroll
    for (int t = 0; t < 8; ++t) {
        if (!valid[t]) continue;
        float g = gw[t];
        float* orow = out + (size_t)tok[t] * ND + lane;
        #pragma unroll
        for (int j = 0; j < 16; ++j) atomicAdd(orow + 64*j, g * acc[t][j]);
    }
}

// ---------------- launch ----------------
extern "C" void kernel_launch(void* const* d_in, const int* in_sizes, int n_in,
                              void* d_out, int out_size, void* d_ws, size_t ws_size,
                              hipStream_t stream) {
    const float* x  = (const float*)d_in[0];
    const float* rw = (const float*)d_in[1];
    const float* w1 = (const float*)d_in[2];
    const float* w2 = (const float*)d_in[3];
    float* out = (float*)d_out;

    int*   ctrl       = (int*)d_ws;
    int*   topk_idx   = ctrl + 32;
    float* topk_w     = (float*)(topk_idx + NPAIR);
    int*   bucket_tok = (int*)(topk_w + NPAIR);
    float* bucket_gw  = (float*)(bucket_tok + NPAIR);

    const size_t CTRL_BYTES = (size_t)1 << 19;                       // 512 KB
    const size_t WT_BYTES   = (size_t)NE * NH * ND * sizeof(u16);    // 32 MB each
    const size_t NEED       = CTRL_BYTES + 2 * WT_BYTES;

    hipMemsetAsync(d_out, 0, (size_t)NTOK * ND * sizeof(float), stream);
    hipMemsetAsync(d_ws, 0, 128, stream);

    router_topk<<<NTOK, 256, 0, stream>>>(x, rw, topk_idx, topk_w, ctrl);
    prefix_offsets<<<1, 1, 0, stream>>>(ctrl);
    scatter_tokens<<<NTOK/256, 256, 0, stream>>>(topk_idx, topk_w, ctrl, bucket_tok, bucket_gw);

    if (ws_size >= NEED) {
        u16* w1t = (u16*)((char*)d_ws + CTRL_BYTES);
        u16* w2t = (u16*)((char*)d_ws + CTRL_BYTES + WT_BYTES);
        transpose_cvt<<<dim3(512, NE), 256, 0, stream>>>(w1, w1t, ND, NH);   // [D][H]->[H][D]
        transpose_cvt<<<dim3(512, NE), 256, 0, stream>>>(w2, w2t, NH, ND);   // [H][D]->[D][H]

        size_t shbytes = (size_t)(64 * XB_S + 64 * AL_S) * sizeof(u16);      // 149504 B
        dim3 grid(NE, NPAIR / TT);
        moe_mlp_mfma<<<grid, 512, shbytes, stream>>>(x, w1t, w2t, bucket_tok, bucket_gw, ctrl, out);
    } else {
        size_t shbytes = (8192 + 4096) * sizeof(float);
        dim3 grid(NPAIR/64, NE);
        moe_mlp<<<grid, 512, shbytes, stream>>>(x, w1, w2, bucket_tok, bucket_gw, ctrl, out);
    }
}

// Round 4
// 566.779 us; speedup vs baseline: 23.6745x; 1.8276x over previous
//
#include <hip/hip_runtime.h>
#include <hip/hip_bf16.h>
#include <stdint.h>

// MoELayer: B=4, T=2048, D=1024, E=8, H=2048, K=2
#define ND    1024
#define NE    8
#define NH    2048
#define NTOK  8192
#define NPAIR (NTOK*2)

typedef unsigned short u16;
typedef __attribute__((ext_vector_type(8))) short bf16x8;
typedef __attribute__((ext_vector_type(4))) float f32x4;

__device__ __forceinline__ u16 f2bf(float f) {
    union { float f; unsigned u; } v; v.f = f;
    return (u16)((v.u + 0x7fffu + ((v.u >> 16) & 1u)) >> 16);   // RNE
}

// async global->LDS, 16B per lane. LDS dest is wave-uniform base + lane*16 (HW).
__device__ __forceinline__ void gl_lds16(const void* g, void* l) {
    __builtin_amdgcn_global_load_lds(
        (const __attribute__((address_space(1))) unsigned int*)g,
        (__attribute__((address_space(3))) unsigned int*)l, 16, 0, 0);
}

// ---------------- kernel 1: router (wave per token) ----------------
__global__ __launch_bounds__(256) void router_topk2(
    const float* __restrict__ x, const float* __restrict__ rw,
    int* __restrict__ topk_idx, float* __restrict__ topk_w, int* __restrict__ counts)
{
    const int n    = blockIdx.x * 4 + (threadIdx.x >> 6);
    const int lane = threadIdx.x & 63;
    const float* xr = x + (size_t)n * ND;
    float4 xv[4];
    #pragma unroll
    for (int i = 0; i < 4; ++i) xv[i] = *(const float4*)(xr + lane*16 + i*4);

    float lg[NE];
    #pragma unroll
    for (int e = 0; e < NE; ++e) {
        const float* wr_ = rw + (size_t)e * ND + lane*16;
        float a = 0.f;
        #pragma unroll
        for (int i = 0; i < 4; ++i) {
            float4 wv = *(const float4*)(wr_ + i*4);
            a += xv[i].x*wv.x + xv[i].y*wv.y + xv[i].z*wv.z + xv[i].w*wv.w;
        }
        #pragma unroll
        for (int s = 32; s; s >>= 1) a += __shfl_xor(a, s);
        lg[e] = a;
    }
    if (lane == 0) {
        int i0 = 0; float v0 = lg[0];
        #pragma unroll
        for (int i = 1; i < NE; ++i) { float v = lg[i]; if (v > v0) { v0 = v; i0 = i; } }
        int i1 = -1; float v1 = -3.4e38f;
        #pragma unroll
        for (int i = 0; i < NE; ++i) {
            if (i == i0) continue;
            float v = lg[i]; if (v > v1) { v1 = v; i1 = i; }
        }
        float w0 = 1.f / (1.f + expf(v1 - v0));
        topk_idx[n*2]   = i0;  topk_idx[n*2+1] = i1;
        topk_w [n*2]    = w0;  topk_w [n*2+1]  = 1.f - w0;
        atomicAdd(&counts[i0], 1);
        atomicAdd(&counts[i1], 1);
    }
}

// ---------------- kernel 2: prefix sum over E=8 counts ----------------
__global__ void prefix_offsets(int* __restrict__ ctrl)
{
    int* counts  = ctrl;
    int* cursors = ctrl + 8;
    int* offsets = ctrl + 16;
    int s = 0;
    for (int e = 0; e < NE; ++e) { offsets[e] = s; s += counts[e]; cursors[e] = 0; }
    offsets[NE] = s;
}

// ---------------- kernel 3: scatter tokens into per-expert buckets ----------------
__global__ __launch_bounds__(256) void scatter_tokens(
    const int* __restrict__ topk_idx, const float* __restrict__ topk_w,
    int* __restrict__ ctrl, int* __restrict__ bucket_tok, float* __restrict__ bucket_gw)
{
    const int n = blockIdx.x * blockDim.x + threadIdx.x;
    if (n >= NTOK) return;
    int* cursors = ctrl + 8;
    const int* offsets = ctrl + 16;
    #pragma unroll
    for (int k = 0; k < 2; ++k) {
        int e = topk_idx[n*2 + k];
        int pos = offsets[e] + atomicAdd(&cursors[e], 1);
        bucket_tok[pos] = n;
        bucket_gw [pos] = topk_w[n*2 + k];
    }
}

// ---------------- kernel T: transpose + fp32->bf16 ----------------
__global__ __launch_bounds__(256) void transpose_cvt(
    const float* __restrict__ src, u16* __restrict__ dst, int R, int C)
{
    __shared__ float tb[64][65];
    const int tpc = C >> 6;
    const int tr = blockIdx.x / tpc;
    const int tc = blockIdx.x % tpc;
    src += (size_t)blockIdx.y * R * C;
    dst += (size_t)blockIdx.y * R * C;
    const int tid = threadIdx.x;
    #pragma unroll
    for (int i = 0; i < 4; ++i) {
        int idx = i*256 + tid;
        int r = idx >> 4, c4 = (idx & 15) * 4;
        float4 v = *(const float4*)(src + (size_t)(tr*64 + r)*C + tc*64 + c4);
        tb[r][c4] = v.x; tb[r][c4+1] = v.y; tb[r][c4+2] = v.z; tb[r][c4+3] = v.w;
    }
    __syncthreads();
    #pragma unroll
    for (int i = 0; i < 2; ++i) {
        int idx = i*256 + tid;
        int c = idx >> 3, s8 = (idx & 7) * 8;
        union { u16 u[8]; uint4 v; } pk;
        #pragma unroll
        for (int j = 0; j < 8; ++j) pk.u[j] = f2bf(tb[s8 + j][c]);
        *(uint4*)(dst + (size_t)(tc*64 + c)*R + tr*64 + s8) = pk.v;
    }
}

// ---------------- kernel G: gather + fp32->bf16 (wave per pair row) ----------------
__global__ __launch_bounds__(256) void gather_cvt(
    const float* __restrict__ x, const int* __restrict__ bucket_tok, u16* __restrict__ Xg)
{
    const int pair = blockIdx.x * 4 + (threadIdx.x >> 6);
    const int lane = threadIdx.x & 63;
    const float* xr = x + (size_t)bucket_tok[pair] * ND;
    u16* dr = Xg + (size_t)pair * ND;
    const int d0 = lane * 16;
    float4 a = *(const float4*)(xr + d0);
    float4 b = *(const float4*)(xr + d0 + 4);
    float4 c = *(const float4*)(xr + d0 + 8);
    float4 d = *(const float4*)(xr + d0 + 12);
    union { u16 u[8]; uint4 v; } p0, p1;
    p0.u[0]=f2bf(a.x); p0.u[1]=f2bf(a.y); p0.u[2]=f2bf(a.z); p0.u[3]=f2bf(a.w);
    p0.u[4]=f2bf(b.x); p0.u[5]=f2bf(b.y); p0.u[6]=f2bf(b.z); p0.u[7]=f2bf(b.w);
    p1.u[0]=f2bf(c.x); p1.u[1]=f2bf(c.y); p1.u[2]=f2bf(c.z); p1.u[3]=f2bf(c.w);
    p1.u[4]=f2bf(d.x); p1.u[5]=f2bf(d.y); p1.u[6]=f2bf(d.z); p1.u[7]=f2bf(d.w);
    *(uint4*)(dr + d0)     = p0.v;
    *(uint4*)(dr + d0 + 8) = p1.v;
}

// ---------------- pass GEMM: C[128m x 128n] tiles, NT layout, bf16 MFMA ----------------
// A rows: token-pairs (pass1: Xg, pass2: A1). B rows: weight rows, K-contiguous.
// Staging: global_load_lds w=16, double-buffered, XOR-swizzled (chunk ^= row&7) both sides.
// EPI=0: A1 = bf16(relu^2(C)).  EPI=1: out[tok] += gate * C (f32 atomics).
template<int KSTEPS, int EPI>
__global__ __launch_bounds__(256, 2) void pass_gemm(
    const u16* __restrict__ Amat, const u16* __restrict__ Bmat,
    const int* __restrict__ bucket_tok, const float* __restrict__ bucket_gw,
    const int* __restrict__ ctrl,
    u16* __restrict__ A1out, float* __restrict__ out)
{
    const int K   = KSTEPS * 64;
    const int e   = blockIdx.z;
    const int nt0 = blockIdx.x * 128;
    const int mt0 = blockIdx.y * 128;
    const int* offsets = ctrl + 16;
    const int beg = offsets[e];
    const int cnt = offsets[e+1] - beg;
    if (mt0 >= cnt) return;

    extern __shared__ u16 sm[];   // A: [2][128][64] @0 ; B: [2][128][64] @16384 (u16 units)

    const int tid  = threadIdx.x;
    const int wv   = tid >> 6;
    const int lane = tid & 63;
    const int l15  = lane & 15;
    const int grp  = lane >> 4;
    const int wr   = wv >> 1, wc = wv & 1;
    const int rmax = cnt - mt0 - 1;

    const u16* Abase = Amat + (size_t)beg * K;
    const u16* Bb    = Bmat + (size_t)e * NH * ND;   // both passes: rows*K == NH*ND

    const int rsub  = lane >> 3;     // 0..7
    const int csrc0 = lane & 7;      // source chunk pre-swizzle

    auto stage = [&](int buf, int kt) {
        #pragma unroll
        for (int c = 0; c < 4; ++c) {
            int row = c*32 + wv*8 + rsub;
            int chunk = csrc0 ^ (row & 7);            // inverse-swizzled source
            int lrow = row > rmax ? rmax : row;
            const u16* ga = Abase + (size_t)(mt0 + lrow) * K + kt*64 + chunk*8;
            gl_lds16(ga, sm + buf*8192 + c*2048 + wv*512);
            const u16* gb = Bb + (size_t)(nt0 + row) * K + kt*64 + chunk*8;
            gl_lds16(gb, sm + 16384 + buf*8192 + c*2048 + wv*512);
        }
    };

    f32x4 acc[4][4];
    #pragma unroll
    for (int mt = 0; mt < 4; ++mt)
        #pragma unroll
        for (int nt = 0; nt < 4; ++nt) acc[mt][nt] = 0;

    stage(0, 0);
    int cur = 0;
    for (int kt = 0; kt < KSTEPS; ++kt) {
        __syncthreads();                       // buf[cur] staged (vmcnt drain) + prev reads done
        if (kt + 1 < KSTEPS) stage(cur ^ 1, kt + 1);
        const char* As = (const char*)(sm + cur*8192);
        const char* Bs = (const char*)(sm + 16384 + cur*8192);
        #pragma unroll
        for (int kk = 0; kk < 2; ++kk) {
            bf16x8 af[4], bfr[4];
            #pragma unroll
            for (int mt = 0; mt < 4; ++mt) {
                int row = wr*64 + mt*16 + l15;
                int kb  = ((kk*32 + grp*8)*2) ^ ((row & 7) << 4);   // swizzled read
                af[mt] = *(const bf16x8*)(As + row*128 + kb);
            }
            #pragma unroll
            for (int nt = 0; nt < 4; ++nt) {
                int row = wc*64 + nt*16 + l15;
                int kb  = ((kk*32 + grp*8)*2) ^ ((row & 7) << 4);
                bfr[nt] = *(const bf16x8*)(Bs + row*128 + kb);
            }
            #pragma unroll
            for (int mt = 0; mt < 4; ++mt)
                #pragma unroll
                for (int nt = 0; nt < 4; ++nt)
                    acc[mt][nt] = __builtin_amdgcn_mfma_f32_16x16x32_bf16(af[mt], bfr[nt], acc[mt][nt], 0,0,0);
        }
        cur ^= 1;
    }

    // epilogue: D row(token) = grp*4+r, col = l15 (verified mapping)
    #pragma unroll
    for (int mt = 0; mt < 4; ++mt) {
        #pragma unroll
        for (int r = 0; r < 4; ++r) {
            int ml = mt0 + wr*64 + mt*16 + grp*4 + r;
            if (ml >= cnt) continue;
            if (EPI == 0) {
                u16* dst = A1out + (size_t)(beg + ml) * NH + nt0 + wc*64 + l15;
                #pragma unroll
                for (int nt = 0; nt < 4; ++nt) {
                    float v = fmaxf(acc[mt][nt][r], 0.f);
                    dst[nt*16] = f2bf(v * v);
                }
            } else {
                int   p = bucket_tok[beg + ml];
                float g = bucket_gw [beg + ml];
                float* orow = out + (size_t)p * ND + nt0 + wc*64 + l15;
                #pragma unroll
                for (int nt = 0; nt < 4; ++nt)
                    atomicAdd(orow + nt*16, g * acc[mt][nt][r]);
            }
        }
    }
}

// ---------------- fallback tier 2: round-3 fused MFMA kernel (proven) ----------------
#define TT 64
#define HC 128
#define XB_S 1032
#define AL_S 136
__global__ __launch_bounds__(512) void moe_mlp_mfma(
    const float* __restrict__ x, const u16* __restrict__ w1t, const u16* __restrict__ w2t,
    const int* __restrict__ bucket_tok, const float* __restrict__ bucket_gw,
    const int* __restrict__ ctrl, float* __restrict__ out)
{
    const int e = blockIdx.x;
    const int* offsets = ctrl + 16;
    const int beg = offsets[e];
    const int cnt = offsets[e+1] - beg;
    const int tile = blockIdx.y;
    if (tile * TT >= cnt) return;

    extern __shared__ u16 smem_u[];
    u16* xb    = smem_u;
    u16* albuf = smem_u + 64 * XB_S;

    const int tid  = threadIdx.x;
    const int wv   = tid >> 6;
    const int lane = tid & 63;
    const int l15  = lane & 15;
    const int grp  = lane >> 4;
    const int kl   = grp * 8;

    {
        const int t = tid >> 3, part = tid & 7;
        int s = tile * TT + t;
        int bi = beg + (s < cnt ? s : cnt - 1);
        int p = bucket_tok[bi];
        const float* xr = x + (size_t)p * ND;
        #pragma unroll 4
        for (int i = 0; i < 32; ++i) {
            int d = part * 4 + i * 32;
            float4 xv = *(const float4*)(xr + d);
            ushort4 u4;
            u4.x = f2bf(xv.x); u4.y = f2bf(xv.y); u4.z = f2bf(xv.z); u4.w = f2bf(xv.w);
            *(ushort4*)&xb[t * XB_S + d] = u4;
        }
    }
    __syncthreads();

    const u16* w1t_e = w1t + (size_t)e * NH * ND;
    const u16* w2t_e = w2t + (size_t)e * ND * NH;
    const int dbase = wv * 128;

    f32x4 accY[8][4];
    #pragma unroll
    for (int dt = 0; dt < 8; ++dt)
        #pragma unroll
        for (int tt = 0; tt < 4; ++tt) accY[dt][tt] = 0;

    for (int hc = 0; hc < NH; hc += HC) {
        f32x4 c1[4];
        #pragma unroll
        for (int tt = 0; tt < 4; ++tt) c1[tt] = 0;
        const u16* ap = w1t_e + (size_t)(hc + wv*16 + l15) * ND + kl;
        for (int ks = 0; ks < 32; ++ks) {
            bf16x8 a = *(const bf16x8*)(ap + ks*32);
            #pragma unroll
            for (int tt = 0; tt < 4; ++tt) {
                bf16x8 b = *(const bf16x8*)&xb[(tt*16 + l15) * XB_S + ks*32 + kl];
                c1[tt] = __builtin_amdgcn_mfma_f32_16x16x32_bf16(a, b, c1[tt], 0,0,0);
            }
        }
        #pragma unroll
        for (int tt = 0; tt < 4; ++tt)
            #pragma unroll
            for (int r = 0; r < 4; ++r) {
                float v = fmaxf(c1[tt][r], 0.f);
                albuf[(tt*16 + l15) * AL_S + (wv*16 + grp*4 + r)] = f2bf(v * v);
            }
        __syncthreads();

        #pragma unroll
        for (int ks = 0; ks < 4; ++ks) {
            bf16x8 bb[4];
            #pragma unroll
            for (int tt = 0; tt < 4; ++tt)
                bb[tt] = *(const bf16x8*)&albuf[(tt*16 + l15) * AL_S + ks*32 + kl];
            const u16* w2p = w2t_e + (size_t)(dbase + l15) * NH + hc + ks*32 + kl;
            #pragma unroll
            for (int dt = 0; dt < 8; ++dt) {
                bf16x8 a = *(const bf16x8*)(w2p + (size_t)dt * 16 * NH);
                #pragma unroll
                for (int tt = 0; tt < 4; ++tt)
                    accY[dt][tt] = __builtin_amdgcn_mfma_f32_16x16x32_bf16(a, bb[tt], accY[dt][tt], 0,0,0);
            }
        }
        __syncthreads();
    }

    #pragma unroll
    for (int tt = 0; tt < 4; ++tt) {
        int s = tile * TT + tt*16 + l15;
        if (s >= cnt) continue;
        int p = bucket_tok[beg + s];
        float g = bucket_gw[beg + s];
        float* orow = out + (size_t)p * ND + dbase + grp*4;
        #pragma unroll
        for (int dt = 0; dt < 8; ++dt)
            #pragma unroll
            for (int r = 0; r < 4; ++r)
                atomicAdd(orow + dt*16 + r, g * accY[dt][tt][r]);
    }
}

// ---------------- fallback tier 3: fp32 vector MLP ----------------
__global__ __launch_bounds__(512, 2) void moe_mlp(
    const float* __restrict__ x, const float* __restrict__ w1, const float* __restrict__ w2,
    const int* __restrict__ bucket_tok, const float* __restrict__ bucket_gw,
    const int* __restrict__ ctrl, float* __restrict__ out)
{
    const int e = blockIdx.y;
    const int* offsets = ctrl + 16;
    const int beg = offsets[e];
    const int cnt = offsets[e+1] - beg;
    const int tile = blockIdx.x;
    if (tile * 64 >= cnt) return;

    extern __shared__ float smem[];
    float* wstage = smem;
    float* hbuf   = smem + 8192;

    const int tid  = threadIdx.x;
    const int wave = tid >> 6;
    const int lane = tid & 63;

    int tok[8]; float gw[8]; bool valid[8];
    const float* xrow[8];
    #pragma unroll
    for (int t = 0; t < 8; ++t) {
        int s = tile*64 + wave*8 + t;
        valid[t] = (s < cnt);
        int bi = beg + (valid[t] ? s : 0);
        tok[t]  = bucket_tok[bi];
        gw[t]   = bucket_gw[bi];
        xrow[t] = x + (size_t)tok[t] * ND;
    }
    const float* w1e = w1 + (size_t)e * ND * NH;
    const float* w2e = w2 + (size_t)e * NH * ND;

    float acc[8][16];
    #pragma unroll
    for (int t = 0; t < 8; ++t)
        #pragma unroll
        for (int j = 0; j < 16; ++j) acc[t][j] = 0.f;

    for (int hb = 0; hb < NH; hb += 64) {
        float hacc[8] = {0,0,0,0,0,0,0,0};
        for (int s4 = 0; s4 < 8; ++s4) {
            __syncthreads();
            const int dbase = s4 * 128;
            #pragma unroll
            for (int r = 0; r < 4; ++r) {
                int i4 = r*512 + tid;
                int dd = i4 >> 4, h4 = i4 & 15;
                *(float4*)(wstage + (size_t)i4*4) =
                    *(const float4*)(w1e + (size_t)(dbase+dd)*NH + hb + h4*4);
            }
            __syncthreads();
            for (int d4 = 0; d4 < 32; ++d4) {
                float4 xv[8];
                #pragma unroll
                for (int t = 0; t < 8; ++t)
                    xv[t] = *(const float4*)(xrow[t] + dbase + d4*4);
                #pragma unroll
                for (int q = 0; q < 4; ++q) {
                    float wvv = wstage[(d4*4+q)*64 + lane];
                    #pragma unroll
                    for (int t = 0; t < 8; ++t) {
                        float xq = (q==0)?xv[t].x:(q==1)?xv[t].y:(q==2)?xv[t].z:xv[t].w;
                        hacc[t] = fmaf(xq, wvv, hacc[t]);
                    }
                }
            }
        }
        #pragma unroll
        for (int t = 0; t < 8; ++t) {
            float hv = fmaxf(hacc[t], 0.f);
            hbuf[(wave*8+t)*64 + lane] = hv * hv;
        }
        for (int s2 = 0; s2 < 8; ++s2) {
            __syncthreads();
            #pragma unroll
            for (int r = 0; r < 4; ++r) {
                int i4 = r*512 + tid;
                int hh = i4 >> 8, d4i = i4 & 255;
                *(float4*)(wstage + (size_t)i4*4) =
                    *(const float4*)(w2e + (size_t)(hb + s2*8 + hh)*ND + d4i*4);
            }
            __syncthreads();
            for (int hh = 0; hh < 8; ++hh) {
                float av[8];
                #pragma unroll
                for (int t = 0; t < 8; ++t) av[t] = hbuf[(wave*8+t)*64 + s2*8 + hh];
                #pragma unroll
                for (int j = 0; j < 16; ++j) {
                    float wvv = wstage[hh*1024 + lane + 64*j];
                    #pragma unroll
                    for (int t = 0; t < 8; ++t) acc[t][j] = fmaf(av[t], wvv, acc[t][j]);
                }
            }
        }
    }
    #pragma unroll
    for (int t = 0; t < 8; ++t) {
        if (!valid[t]) continue;
        float g = gw[t];
        float* orow = out + (size_t)tok[t] * ND + lane;
        #pragma unroll
        for (int j = 0; j < 16; ++j) atomicAdd(orow + 64*j, g * acc[t][j]);
    }
}

// ---------------- launch ----------------
extern "C" void kernel_launch(void* const* d_in, const int* in_sizes, int n_in,
                              void* d_out, int out_size, void* d_ws, size_t ws_size,
                              hipStream_t stream) {
    const float* x  = (const float*)d_in[0];
    const float* rw = (const float*)d_in[1];
    const float* w1 = (const float*)d_in[2];
    const float* w2 = (const float*)d_in[3];
    float* out = (float*)d_out;

    int*   ctrl       = (int*)d_ws;
    int*   topk_idx   = ctrl + 32;
    float* topk_w     = (float*)(topk_idx + NPAIR);
    int*   bucket_tok = (int*)(topk_w + NPAIR);
    float* bucket_gw  = (float*)(bucket_tok + NPAIR);

    const size_t CTRL_BYTES = (size_t)1 << 19;                       // 512 KB
    const size_t WT_BYTES   = (size_t)NE * NH * ND * sizeof(u16);    // 32 MB
    const size_t A1_BYTES   = (size_t)NPAIR * NH * sizeof(u16);      // 64 MB
    const size_t NEED1      = CTRL_BYTES + 2 * WT_BYTES;             // 64.5 MB (tier 2)
    const size_t NEED2      = CTRL_BYTES + 2 * WT_BYTES + A1_BYTES;  // 128.5 MB (tier 1)

    hipMemsetAsync(d_out, 0, (size_t)NTOK * ND * sizeof(float), stream);
    hipMemsetAsync(d_ws, 0, 128, stream);

    router_topk2<<<NTOK/4, 256, 0, stream>>>(x, rw, topk_idx, topk_w, ctrl);
    prefix_offsets<<<1, 1, 0, stream>>>(ctrl);
    scatter_tokens<<<NTOK/256, 256, 0, stream>>>(topk_idx, topk_w, ctrl, bucket_tok, bucket_gw);

    if (ws_size >= NEED2) {
        u16* w1t = (u16*)((char*)d_ws + CTRL_BYTES);                 // 32 MB (pass 1)
        u16* shr = (u16*)((char*)d_ws + CTRL_BYTES + WT_BYTES);      // 32 MB: Xg then w2t
        u16* A1  = (u16*)((char*)d_ws + CTRL_BYTES + 2*WT_BYTES);    // 64 MB

        transpose_cvt<<<dim3(512, NE), 256, 0, stream>>>(w1, w1t, ND, NH);  // [D][H]->[H][D]
        gather_cvt<<<NPAIR/4, 256, 0, stream>>>(x, bucket_tok, shr);        // Xg

        pass_gemm<16, 0><<<dim3(NH/128, 128, NE), 256, 65536, stream>>>(
            shr, w1t, bucket_tok, bucket_gw, ctrl, A1, nullptr);

        transpose_cvt<<<dim3(512, NE), 256, 0, stream>>>(w2, shr, NH, ND);  // w2t (overwrites Xg)

        pass_gemm<32, 1><<<dim3(ND/128, 128, NE), 256, 65536, stream>>>(
            A1, shr, bucket_tok, bucket_gw, ctrl, nullptr, out);
    } else if (ws_size >= NEED1) {
        u16* w1t = (u16*)((char*)d_ws + CTRL_BYTES);
        u16* w2t = (u16*)((char*)d_ws + CTRL_BYTES + WT_BYTES);
        transpose_cvt<<<dim3(512, NE), 256, 0, stream>>>(w1, w1t, ND, NH);
        transpose_cvt<<<dim3(512, NE), 256, 0, stream>>>(w2, w2t, NH, ND);
        size_t shbytes = (size_t)(64 * XB_S + 64 * AL_S) * sizeof(u16);
        dim3 grid(NE, NPAIR / TT);
        moe_mlp_mfma<<<grid, 512, shbytes, stream>>>(x, w1t, w2t, bucket_tok, bucket_gw, ctrl, out);
    } else {
        size_t shbytes = (8192 + 4096) * sizeof(float);
        dim3 grid(NPAIR/64, NE);
        moe_mlp<<<grid, 512, shbytes, stream>>>(x, w1, w2, bucket_tok, bucket_gw, ctrl, out);
    }
}

// Round 5
// 316.078 us; speedup vs baseline: 42.4522x; 1.7932x over previous
//
#include <hip/hip_runtime.h>
#include <hip/hip_bf16.h>
#include <stdint.h>

// MoELayer: B=4, T=2048, D=1024, E=8, H=2048, K=2
#define ND    1024
#define NE    8
#define NH    2048
#define NTOK  8192
#define NPAIR (NTOK*2)

typedef unsigned short u16;
typedef __attribute__((ext_vector_type(8))) short bf16x8;
typedef __attribute__((ext_vector_type(4))) float f32x4;

__device__ __forceinline__ u16 f2bf(float f) {
    union { float f; unsigned u; } v; v.f = f;
    return (u16)((v.u + 0x7fffu + ((v.u >> 16) & 1u)) >> 16);   // RNE
}

// async global->LDS, 16B per lane. LDS dest is wave-uniform base + lane*16 (HW).
__device__ __forceinline__ void gl_lds16(const void* g, void* l) {
    __builtin_amdgcn_global_load_lds(
        (const __attribute__((address_space(1))) unsigned int*)g,
        (__attribute__((address_space(3))) unsigned int*)l, 16, 0, 0);
}

// ctrl layout (ints):
//   [16..24]   offsets[9]            (expert bucket starts; pass_gemm reads ctrl+16)
//   [32..288)  blockcounts[32][8]
//   [288..544) bbase[32][8]          (per-block per-expert bucket base)
//   [544..)    topk_idx[NPAIR], then topk_w, bucket_tok, bucket_gw
#define CTRL_OFFS  16
#define CTRL_BC    32
#define CTRL_BB    288
#define CTRL_TOPK  544

// ---------------- kernel 1: router (wave per token, NO atomics) ----------------
__global__ __launch_bounds__(256) void router_topk2(
    const float* __restrict__ x, const float* __restrict__ rw,
    int* __restrict__ topk_idx, float* __restrict__ topk_w)
{
    const int n    = blockIdx.x * 4 + (threadIdx.x >> 6);
    const int lane = threadIdx.x & 63;
    const float* xr = x + (size_t)n * ND;
    float4 xv[4];
    #pragma unroll
    for (int i = 0; i < 4; ++i) xv[i] = *(const float4*)(xr + lane*16 + i*4);

    float lg[NE];
    #pragma unroll
    for (int e = 0; e < NE; ++e) {
        const float* wr_ = rw + (size_t)e * ND + lane*16;
        float a = 0.f;
        #pragma unroll
        for (int i = 0; i < 4; ++i) {
            float4 wv = *(const float4*)(wr_ + i*4);
            a += xv[i].x*wv.x + xv[i].y*wv.y + xv[i].z*wv.z + xv[i].w*wv.w;
        }
        #pragma unroll
        for (int s = 32; s; s >>= 1) a += __shfl_xor(a, s);
        lg[e] = a;
    }
    if (lane == 0) {
        int i0 = 0; float v0 = lg[0];
        #pragma unroll
        for (int i = 1; i < NE; ++i) { float v = lg[i]; if (v > v0) { v0 = v; i0 = i; } }
        int i1 = -1; float v1 = -3.4e38f;
        #pragma unroll
        for (int i = 0; i < NE; ++i) {
            if (i == i0) continue;
            float v = lg[i]; if (v > v1) { v1 = v; i1 = i; }
        }
        float w0 = 1.f / (1.f + expf(v1 - v0));
        topk_idx[n*2]   = i0;  topk_idx[n*2+1] = i1;
        topk_w [n*2]    = w0;  topk_w [n*2+1]  = 1.f - w0;
    }
}

// ---------------- kernel 2: per-block expert histogram (LDS-aggregated) ----------------
__global__ __launch_bounds__(256) void hist_blocks(
    const int* __restrict__ topk_idx, int* __restrict__ blockcounts)
{
    __shared__ int c[NE];
    const int tid = threadIdx.x;
    if (tid < NE) c[tid] = 0;
    __syncthreads();
    const int n = blockIdx.x * 256 + tid;
    atomicAdd(&c[topk_idx[n*2]],   1);
    atomicAdd(&c[topk_idx[n*2+1]], 1);
    __syncthreads();
    if (tid < NE) blockcounts[blockIdx.x * NE + tid] = c[tid];
}

// ---------------- kernel 3: prefix (1 wave): offsets[9] + bbase[32][8] ----------------
__global__ void prefix2(int* __restrict__ ctrl)
{
    const int e = threadIdx.x;
    const int* bc = ctrl + CTRL_BC;
    int* offsets  = ctrl + CTRL_OFFS;
    int* bbase    = ctrl + CTRL_BB;
    if (e < NE) {
        int run = 0;
        int tmp[32];
        #pragma unroll
        for (int b = 0; b < 32; ++b) { tmp[b] = run; run += bc[b*NE + e]; }
        int total = run, pre = 0;
        #pragma unroll
        for (int i = 0; i < NE; ++i) {
            int v = __shfl(total, i);
            if (i < e) pre += v;
        }
        offsets[e] = pre;
        if (e == NE-1) offsets[NE] = pre + total;
        #pragma unroll
        for (int b = 0; b < 32; ++b) bbase[b*NE + e] = pre + tmp[b];
    }
}

// ---------------- kernel 4: stable deterministic scatter (ballot ranks, no atomics) ----------------
__global__ __launch_bounds__(256) void scatter2(
    const int* __restrict__ topk_idx, const float* __restrict__ topk_w,
    const int* __restrict__ ctrl,
    int* __restrict__ bucket_tok, float* __restrict__ bucket_gw)
{
    __shared__ int wc[4][NE];
    const int b = blockIdx.x, tid = threadIdx.x;
    const int w = tid >> 6, l = tid & 63;
    const int n = b*256 + tid;
    const int e0 = topk_idx[n*2], e1 = topk_idx[n*2+1];
    const unsigned long long lt = (1ULL << l) - 1ULL;

    int rank0 = 0, rank1 = 0;
    #pragma unroll
    for (int e = 0; e < NE; ++e) {
        unsigned long long m0 = __ballot(e0 == e);
        unsigned long long m1 = __ballot(e1 == e);
        int c0 = __popcll(m0);
        if (e0 == e) rank0 = __popcll(m0 & lt);
        if (e1 == e) rank1 = c0 + __popcll(m1 & lt);
        if (l == 0) wc[w][e] = c0 + __popcll(m1);
    }
    __syncthreads();
    const int* bbase = ctrl + CTRL_BB;
    int wo0 = 0, wo1 = 0;
    #pragma unroll
    for (int w2 = 0; w2 < 4; ++w2) {
        if (w2 < w) { wo0 += wc[w2][e0]; wo1 += wc[w2][e1]; }
    }
    int p0 = bbase[b*NE + e0] + wo0 + rank0;
    int p1 = bbase[b*NE + e1] + wo1 + rank1;
    bucket_tok[p0] = n;  bucket_gw[p0] = topk_w[n*2];
    bucket_tok[p1] = n;  bucket_gw[p1] = topk_w[n*2+1];
}

// ---------------- kernel T: transpose + fp32->bf16 ----------------
__global__ __launch_bounds__(256) void transpose_cvt(
    const float* __restrict__ src, u16* __restrict__ dst, int R, int C)
{
    __shared__ float tb[64][65];
    const int tpc = C >> 6;
    const int tr = blockIdx.x / tpc;
    const int tc = blockIdx.x % tpc;
    src += (size_t)blockIdx.y * R * C;
    dst += (size_t)blockIdx.y * R * C;
    const int tid = threadIdx.x;
    #pragma unroll
    for (int i = 0; i < 4; ++i) {
        int idx = i*256 + tid;
        int r = idx >> 4, c4 = (idx & 15) * 4;
        float4 v = *(const float4*)(src + (size_t)(tr*64 + r)*C + tc*64 + c4);
        tb[r][c4] = v.x; tb[r][c4+1] = v.y; tb[r][c4+2] = v.z; tb[r][c4+3] = v.w;
    }
    __syncthreads();
    #pragma unroll
    for (int i = 0; i < 2; ++i) {
        int idx = i*256 + tid;
        int c = idx >> 3, s8 = (idx & 7) * 8;
        union { u16 u[8]; uint4 v; } pk;
        #pragma unroll
        for (int j = 0; j < 8; ++j) pk.u[j] = f2bf(tb[s8 + j][c]);
        *(uint4*)(dst + (size_t)(tc*64 + c)*R + tr*64 + s8) = pk.v;
    }
}

// ---------------- kernel G: gather + fp32->bf16 (wave per pair row) ----------------
__global__ __launch_bounds__(256) void gather_cvt(
    const float* __restrict__ x, const int* __restrict__ bucket_tok, u16* __restrict__ Xg)
{
    const int pair = blockIdx.x * 4 + (threadIdx.x >> 6);
    const int lane = threadIdx.x & 63;
    const float* xr = x + (size_t)bucket_tok[pair] * ND;
    u16* dr = Xg + (size_t)pair * ND;
    const int d0 = lane * 16;
    float4 a = *(const float4*)(xr + d0);
    float4 b = *(const float4*)(xr + d0 + 4);
    float4 c = *(const float4*)(xr + d0 + 8);
    float4 d = *(const float4*)(xr + d0 + 12);
    union { u16 u[8]; uint4 v; } p0, p1;
    p0.u[0]=f2bf(a.x); p0.u[1]=f2bf(a.y); p0.u[2]=f2bf(a.z); p0.u[3]=f2bf(a.w);
    p0.u[4]=f2bf(b.x); p0.u[5]=f2bf(b.y); p0.u[6]=f2bf(b.z); p0.u[7]=f2bf(b.w);
    p1.u[0]=f2bf(c.x); p1.u[1]=f2bf(c.y); p1.u[2]=f2bf(c.z); p1.u[3]=f2bf(c.w);
    p1.u[4]=f2bf(d.x); p1.u[5]=f2bf(d.y); p1.u[6]=f2bf(d.z); p1.u[7]=f2bf(d.w);
    *(uint4*)(dr + d0)     = p0.v;
    *(uint4*)(dr + d0 + 8) = p1.v;
}

// ---------------- pass GEMM: C[128m x 128n] tiles, NT layout, bf16 MFMA ----------------
// Staging: global_load_lds w=16, double-buffered, XOR-swizzled (chunk ^= row&7) both sides.
// EPI=0: A1 = bf16(relu^2(C)).  EPI=1: out[tok] += gate * C (f32 atomics).
template<int KSTEPS, int EPI>
__global__ __launch_bounds__(256, 2) void pass_gemm(
    const u16* __restrict__ Amat, const u16* __restrict__ Bmat,
    const int* __restrict__ bucket_tok, const float* __restrict__ bucket_gw,
    const int* __restrict__ ctrl,
    u16* __restrict__ A1out, float* __restrict__ out)
{
    const int K   = KSTEPS * 64;
    const int e   = blockIdx.z;
    const int nt0 = blockIdx.x * 128;
    const int mt0 = blockIdx.y * 128;
    const int* offsets = ctrl + CTRL_OFFS;
    const int beg = offsets[e];
    const int cnt = offsets[e+1] - beg;
    if (mt0 >= cnt) return;

    extern __shared__ u16 sm[];   // A: [2][128][64] @0 ; B: [2][128][64] @16384 (u16 units)

    const int tid  = threadIdx.x;
    const int wv   = tid >> 6;
    const int lane = tid & 63;
    const int l15  = lane & 15;
    const int grp  = lane >> 4;
    const int wr   = wv >> 1, wc = wv & 1;
    const int rmax = cnt - mt0 - 1;

    const u16* Abase = Amat + (size_t)beg * K;
    const u16* Bb    = Bmat + (size_t)e * NH * ND;

    const int rsub  = lane >> 3;
    const int csrc0 = lane & 7;

    auto stage = [&](int buf, int kt) {
        #pragma unroll
        for (int c = 0; c < 4; ++c) {
            int row = c*32 + wv*8 + rsub;
            int chunk = csrc0 ^ (row & 7);
            int lrow = row > rmax ? rmax : row;
            const u16* ga = Abase + (size_t)(mt0 + lrow) * K + kt*64 + chunk*8;
            gl_lds16(ga, sm + buf*8192 + c*2048 + wv*512);
            const u16* gb = Bb + (size_t)(nt0 + row) * K + kt*64 + chunk*8;
            gl_lds16(gb, sm + 16384 + buf*8192 + c*2048 + wv*512);
        }
    };

    f32x4 acc[4][4];
    #pragma unroll
    for (int mt = 0; mt < 4; ++mt)
        #pragma unroll
        for (int nt = 0; nt < 4; ++nt) acc[mt][nt] = 0;

    stage(0, 0);
    int cur = 0;
    for (int kt = 0; kt < KSTEPS; ++kt) {
        __syncthreads();
        if (kt + 1 < KSTEPS) stage(cur ^ 1, kt + 1);
        const char* As = (const char*)(sm + cur*8192);
        const char* Bs = (const char*)(sm + 16384 + cur*8192);
        #pragma unroll
        for (int kk = 0; kk < 2; ++kk) {
            bf16x8 af[4], bfr[4];
            #pragma unroll
            for (int mt = 0; mt < 4; ++mt) {
                int row = wr*64 + mt*16 + l15;
                int kb  = ((kk*32 + grp*8)*2) ^ ((row & 7) << 4);
                af[mt] = *(const bf16x8*)(As + row*128 + kb);
            }
            #pragma unroll
            for (int nt = 0; nt < 4; ++nt) {
                int row = wc*64 + nt*16 + l15;
                int kb  = ((kk*32 + grp*8)*2) ^ ((row & 7) << 4);
                bfr[nt] = *(const bf16x8*)(Bs + row*128 + kb);
            }
            #pragma unroll
            for (int mt = 0; mt < 4; ++mt)
                #pragma unroll
                for (int nt = 0; nt < 4; ++nt)
                    acc[mt][nt] = __builtin_amdgcn_mfma_f32_16x16x32_bf16(af[mt], bfr[nt], acc[mt][nt], 0,0,0);
        }
        cur ^= 1;
    }

    #pragma unroll
    for (int mt = 0; mt < 4; ++mt) {
        #pragma unroll
        for (int r = 0; r < 4; ++r) {
            int ml = mt0 + wr*64 + mt*16 + grp*4 + r;
            if (ml >= cnt) continue;
            if (EPI == 0) {
                u16* dst = A1out + (size_t)(beg + ml) * NH + nt0 + wc*64 + l15;
                #pragma unroll
                for (int nt = 0; nt < 4; ++nt) {
                    float v = fmaxf(acc[mt][nt][r], 0.f);
                    dst[nt*16] = f2bf(v * v);
                }
            } else {
                int   p = bucket_tok[beg + ml];
                float g = bucket_gw [beg + ml];
                float* orow = out + (size_t)p * ND + nt0 + wc*64 + l15;
                #pragma unroll
                for (int nt = 0; nt < 4; ++nt)
                    atomicAdd(orow + nt*16, g * acc[mt][nt][r]);
            }
        }
    }
}

// ---------------- fallback tier 2: round-3 fused MFMA kernel (proven) ----------------
#define TT 64
#define HC 128
#define XB_S 1032
#define AL_S 136
__global__ __launch_bounds__(512) void moe_mlp_mfma(
    const float* __restrict__ x, const u16* __restrict__ w1t, const u16* __restrict__ w2t,
    const int* __restrict__ bucket_tok, const float* __restrict__ bucket_gw,
    const int* __restrict__ ctrl, float* __restrict__ out)
{
    const int e = blockIdx.x;
    const int* offsets = ctrl + CTRL_OFFS;
    const int beg = offsets[e];
    const int cnt = offsets[e+1] - beg;
    const int tile = blockIdx.y;
    if (tile * TT >= cnt) return;

    extern __shared__ u16 smem_u[];
    u16* xb    = smem_u;
    u16* albuf = smem_u + 64 * XB_S;

    const int tid  = threadIdx.x;
    const int wv   = tid >> 6;
    const int lane = tid & 63;
    const int l15  = lane & 15;
    const int grp  = lane >> 4;
    const int kl   = grp * 8;

    {
        const int t = tid >> 3, part = tid & 7;
        int s = tile * TT + t;
        int bi = beg + (s < cnt ? s : cnt - 1);
        int p = bucket_tok[bi];
        const float* xr = x + (size_t)p * ND;
        #pragma unroll 4
        for (int i = 0; i < 32; ++i) {
            int d = part * 4 + i * 32;
            float4 xv = *(const float4*)(xr + d);
            ushort4 u4;
            u4.x = f2bf(xv.x); u4.y = f2bf(xv.y); u4.z = f2bf(xv.z); u4.w = f2bf(xv.w);
            *(ushort4*)&xb[t * XB_S + d] = u4;
        }
    }
    __syncthreads();

    const u16* w1t_e = w1t + (size_t)e * NH * ND;
    const u16* w2t_e = w2t + (size_t)e * ND * NH;
    const int dbase = wv * 128;

    f32x4 accY[8][4];
    #pragma unroll
    for (int dt = 0; dt < 8; ++dt)
        #pragma unroll
        for (int tt = 0; tt < 4; ++tt) accY[dt][tt] = 0;

    for (int hc = 0; hc < NH; hc += HC) {
        f32x4 c1[4];
        #pragma unroll
        for (int tt = 0; tt < 4; ++tt) c1[tt] = 0;
        const u16* ap = w1t_e + (size_t)(hc + wv*16 + l15) * ND + kl;
        for (int ks = 0; ks < 32; ++ks) {
            bf16x8 a = *(const bf16x8*)(ap + ks*32);
            #pragma unroll
            for (int tt = 0; tt < 4; ++tt) {
                bf16x8 b = *(const bf16x8*)&xb[(tt*16 + l15) * XB_S + ks*32 + kl];
                c1[tt] = __builtin_amdgcn_mfma_f32_16x16x32_bf16(a, b, c1[tt], 0,0,0);
            }
        }
        #pragma unroll
        for (int tt = 0; tt < 4; ++tt)
            #pragma unroll
            for (int r = 0; r < 4; ++r) {
                float v = fmaxf(c1[tt][r], 0.f);
                albuf[(tt*16 + l15) * AL_S + (wv*16 + grp*4 + r)] = f2bf(v * v);
            }
        __syncthreads();

        #pragma unroll
        for (int ks = 0; ks < 4; ++ks) {
            bf16x8 bb[4];
            #pragma unroll
            for (int tt = 0; tt < 4; ++tt)
                bb[tt] = *(const bf16x8*)&albuf[(tt*16 + l15) * AL_S + ks*32 + kl];
            const u16* w2p = w2t_e + (size_t)(dbase + l15) * NH + hc + ks*32 + kl;
            #pragma unroll
            for (int dt = 0; dt < 8; ++dt) {
                bf16x8 a = *(const bf16x8*)(w2p + (size_t)dt * 16 * NH);
                #pragma unroll
                for (int tt = 0; tt < 4; ++tt)
                    accY[dt][tt] = __builtin_amdgcn_mfma_f32_16x16x32_bf16(a, bb[tt], accY[dt][tt], 0,0,0);
            }
        }
        __syncthreads();
    }

    #pragma unroll
    for (int tt = 0; tt < 4; ++tt) {
        int s = tile * TT + tt*16 + l15;
        if (s >= cnt) continue;
        int p = bucket_tok[beg + s];
        float g = bucket_gw[beg + s];
        float* orow = out + (size_t)p * ND + dbase + grp*4;
        #pragma unroll
        for (int dt = 0; dt < 8; ++dt)
            #pragma unroll
            for (int r = 0; r < 4; ++r)
                atomicAdd(orow + dt*16 + r, g * accY[dt][tt][r]);
    }
}

// ---------------- launch ----------------
extern "C" void kernel_launch(void* const* d_in, const int* in_sizes, int n_in,
                              void* d_out, int out_size, void* d_ws, size_t ws_size,
                              hipStream_t stream) {
    const float* x  = (const float*)d_in[0];
    const float* rw = (const float*)d_in[1];
    const float* w1 = (const float*)d_in[2];
    const float* w2 = (const float*)d_in[3];
    float* out = (float*)d_out;

    int*   ctrl        = (int*)d_ws;
    int*   blockcounts = ctrl + CTRL_BC;
    int*   topk_idx    = ctrl + CTRL_TOPK;
    float* topk_w      = (float*)(topk_idx + NPAIR);
    int*   bucket_tok  = (int*)(topk_w + NPAIR);
    float* bucket_gw   = (float*)(bucket_tok + NPAIR);

    const size_t CTRL_BYTES = (size_t)1 << 19;                       // 512 KB
    const size_t WT_BYTES   = (size_t)NE * NH * ND * sizeof(u16);    // 32 MB
    const size_t A1_BYTES   = (size_t)NPAIR * NH * sizeof(u16);      // 64 MB
    const size_t NEED1      = CTRL_BYTES + 2 * WT_BYTES;             // tier 2
    const size_t NEED2      = CTRL_BYTES + 2 * WT_BYTES + A1_BYTES;  // tier 1

    hipMemsetAsync(d_out, 0, (size_t)NTOK * ND * sizeof(float), stream);

    router_topk2<<<NTOK/4, 256, 0, stream>>>(x, rw, topk_idx, topk_w);
    hist_blocks<<<NTOK/256, 256, 0, stream>>>(topk_idx, blockcounts);
    prefix2<<<1, 64, 0, stream>>>(ctrl);
    scatter2<<<NTOK/256, 256, 0, stream>>>(topk_idx, topk_w, ctrl, bucket_tok, bucket_gw);

    if (ws_size >= NEED2) {
        u16* w1t = (u16*)((char*)d_ws + CTRL_BYTES);
        u16* shr = (u16*)((char*)d_ws + CTRL_BYTES + WT_BYTES);      // Xg then w2t
        u16* A1  = (u16*)((char*)d_ws + CTRL_BYTES + 2*WT_BYTES);

        transpose_cvt<<<dim3(512, NE), 256, 0, stream>>>(w1, w1t, ND, NH);
        gather_cvt<<<NPAIR/4, 256, 0, stream>>>(x, bucket_tok, shr);

        pass_gemm<16, 0><<<dim3(NH/128, 128, NE), 256, 65536, stream>>>(
            shr, w1t, bucket_tok, bucket_gw, ctrl, A1, nullptr);

        transpose_cvt<<<dim3(512, NE), 256, 0, stream>>>(w2, shr, NH, ND);

        pass_gemm<32, 1><<<dim3(ND/128, 128, NE), 256, 65536, stream>>>(
            A1, shr, bucket_tok, bucket_gw, ctrl, nullptr, out);
    } else if (ws_size >= NEED1) {
        u16* w1t = (u16*)((char*)d_ws + CTRL_BYTES);
        u16* w2t = (u16*)((char*)d_ws + CTRL_BYTES + WT_BYTES);
        transpose_cvt<<<dim3(512, NE), 256, 0, stream>>>(w1, w1t, ND, NH);
        transpose_cvt<<<dim3(512, NE), 256, 0, stream>>>(w2, w2t, NH, ND);
        size_t shbytes = (size_t)(64 * XB_S + 64 * AL_S) * sizeof(u16);
        dim3 grid(NE, NPAIR / TT);
        moe_mlp_mfma<<<grid, 512, shbytes, stream>>>(x, w1t, w2t, bucket_tok, bucket_gw, ctrl, out);
    }
}